// Round 8
// baseline (1561.048 us; speedup 1.0000x reference)
//
#include <hip/hip_runtime.h>
#include <hip/hip_cooperative_groups.h>

namespace cg = cooperative_groups;

// Problem constants
constexpr int D  = 128;
constexpr int M  = 8192;
constexpr int L  = 5;
constexpr int K  = 8;
constexpr int KL = 4;
constexpr int G  = 4096;

constexpr int TB   = 64;            // bucket pad granularity
constexpr int PADL = M + K * TB;    // 8704
constexpr int PADG = G + KL * TB;   // 4352

typedef short bf16x8 __attribute__((ext_vector_type(8)));
typedef float f32x4  __attribute__((ext_vector_type(4)));

__device__ __forceinline__ unsigned short f2bf(float x) {
  union { float f; unsigned int u; } c; c.f = x;
  unsigned int u = c.u + 0x7FFF + ((c.u >> 16) & 1);   // RNE
  return (unsigned short)(u >> 16);
}
__device__ __forceinline__ float bf2f(unsigned short h) {
  union { unsigned int u; float f; } c; c.u = ((unsigned int)h) << 16;
  return c.f;
}

__device__ __forceinline__ int xcd_swizzle(int b, int n) {
  int q = n >> 3, r = n & 7, xcd = b & 7, off = b >> 3;
  return (xcd < r ? xcd * (q + 1) : r * (q + 1) + (xcd - r) * q) + off;
}

// All pointers bundled so the cooperative kernel takes one arg.
struct P {
  const int *leaf_ids, *left_idx, *right_idx, *nf_fid, *gt_left, *gt_right, *lf_fid;
  const float *emb, *W1, *b1, *W2, *b2, *W3, *b3, *Wl1, *bl1, *Wl2, *bl2;
  float* out;
  short *hsA, *hsB, *a1s, *a2s, *B1T, *B2T, *B3T, *BL1T, *BL2T;
  int* orders;
};

// ---------------------------------------------------------------------------
// Setup pieces as device functions (shared by coop kernel and fallback).
__device__ __forceinline__ void leaf_unit(int u, const P& p) {
  int idx = u * 256 + threadIdx.x;               // over M*128
  int n = idx >> 7, d = idx & 127;
  float w = p.emb[(size_t)p.leaf_ids[n] * D + d];
  unsigned short hh = f2bf(w);
  p.hsA[n * 256 + d]       = (short)hh;
  p.hsA[n * 256 + 128 + d] = (short)f2bf(w - bf2f(hh));
}

// Weight prep via 64x64 LDS transpose tile (both sides coalesced).
__device__ void prep_tile(int b, const P& p, float (*T)[65]) {
  const float* W; short* BT; int KD, F;
  if      (b < 256) { W = p.W1;  BT = p.B1T;  KD = 256; F = 512; }
  else if (b < 512) { W = p.W2;  BT = p.B2T;  KD = 512; F = 256; b -= 256; }
  else if (b < 576) { W = p.W3;  BT = p.B3T;  KD = 256; F = 128; b -= 512; }
  else if (b < 704) { W = p.Wl1; BT = p.BL1T; KD = 256; F = 512; b -= 576; }
  else              { W = p.Wl2; BT = p.BL2T; KD = 512; F = 128; b -= 704; }
  const int ntd = KD >> 6, ntf = F >> 6;
  const int k  = b / (ntd * ntf), rem = b % (ntd * ntf);
  const int d0 = (rem / ntf) << 6, f0 = (rem % ntf) << 6;
  const int tid = threadIdx.x, ln = tid & 63, w4 = tid >> 6;
  __syncthreads();                               // guard T reuse across tiles
  #pragma unroll
  for (int i = 0; i < 16; ++i) {                 // read rows d, coalesced over f
    int d = w4 * 16 + i;
    T[ln][d] = W[((size_t)k * KD + d0 + d) * F + f0 + ln];
  }
  __syncthreads();
  #pragma unroll
  for (int i = 0; i < 16; ++i) {                 // write rows f, coalesced over d
    int f = w4 * 16 + i;
    float w = T[f][ln];
    unsigned short hi = f2bf(w);
    unsigned short lo = f2bf(w - bf2f(hi));
    size_t base = ((size_t)k * F + f0 + f) * (2 * KD) + d0;
    BT[base + ln]      = (short)hi;
    BT[base + KD + ln] = (short)lo;
  }
}

// Bucket node indices by fid, padded to 64; pad = -1.
__device__ void bucket_body(int b, const P& p, int* cnt, int* cur) {
  const int* fid; int N, Kf, cap; int* outp;
  if (b < L) { fid = p.nf_fid + b * M; N = M; Kf = K;  cap = PADL; outp = p.orders + b * PADL; }
  else       { fid = p.lf_fid;         N = G; Kf = KL; cap = PADG; outp = p.orders + L * PADL; }
  int tid = threadIdx.x;
  if (tid < Kf) cnt[tid] = 0;
  __syncthreads();
  for (int i = tid; i < N; i += 256) atomicAdd(&cnt[fid[i]], 1);
  __syncthreads();
  if (tid == 0) {
    int off = 0;
    for (int k = 0; k < Kf; ++k) { cur[k] = off; off += ((cnt[k] + TB - 1) / TB) * TB; }
  }
  __syncthreads();
  for (int i = tid; i < cap; i += 256) outp[i] = -1;
  __syncthreads();
  for (int i = tid; i < N; i += 256) {
    int kk = fid[i];
    int pos = atomicAdd(&cur[kk], 1);
    outp[pos] = i;
  }
}

// ---------------------------------------------------------------------------
// One GEMM tile = r2's known-best body, verbatim structure (plain
// __syncthreads, dbuf LDS, 2 register prefetch sets, 1 barrier/chunk).
// Entry __syncthreads guards LDS reuse against the previous tile's epilogue.
// Split-bf16 logical K' = 3*KH: A segs {hi,lo,hi}, B segs {hi,hi,lo}.
template<int KH, int NN, int EPI, int FUSED, int TROWS>
__device__ void gemm_tile(
    int bx, int ct,
    const short* __restrict__ A, const short* __restrict__ hsrc,
    const int* __restrict__ gl, const int* __restrict__ gr,
    const short* __restrict__ BT, const float* __restrict__ bias,
    short* __restrict__ Aout, float* __restrict__ outp,
    const int* __restrict__ order, const int* __restrict__ fid,
    short* As, short* Bs, int* nodesS, int* liS, int* riS) {
  constexpr int BK   = 64;
  constexpr int NCH  = 3 * KH / BK;       // 12 or 24 (even)
  constexpr int LDA  = 72;                // 2-way bank alias (free)
  constexpr int ASTR = TROWS * LDA;       // per-buffer strides
  constexpr int BSTR = 128 * LDA;
  constexpr int RF   = TROWS / 32;        // row frags per wave: 2 or 1
  constexpr int TPR  = 256 / TROWS;       // A-staging threads per row: 4 or 8

  const int tid  = threadIdx.x;
  const int row0 = bx * TROWS;

  __syncthreads();                        // LDS reuse guard (prev tile)
  if (tid < TROWS) {
    int node = order[row0 + tid];
    nodesS[tid] = node;
    if (FUSED) {
      liS[tid] = node >= 0 ? gl[node] : 0;
      riS[tid] = node >= 0 ? gr[node] : 0;
    }
  }
  __syncthreads();
  if (nodesS[0] < 0) return;              // fully-padded tile (uniform)
  const int kfn = fid[nodesS[0]];
  const short* __restrict__ Bk = BT + (size_t)kfn * NN * (2 * KH);

  const int lane = tid & 63, wave = tid >> 6;
  const int wr = (wave >> 1) * (TROWS / 2);   // 2x2 waves
  const int wc = wave & 1;
  const int l15 = lane & 15, oct = lane >> 4;

  const int ar = tid / TPR;                   // A staging row [0,TROWS)
  const int ag = (tid % TPR) * (BK / TPR);    // A short offset (16 or 8)
  const int bn = tid >> 1;                    // B staging col-row [0,128)
  const int bg = (tid & 1) * 32;              // B short offset

  f32x4 acc[RF][4];
  #pragma unroll
  for (int i = 0; i < RF; ++i)
    #pragma unroll
    for (int j = 0; j < 4; ++j) acc[i][j] = (f32x4)0.f;

  auto loadB_to = [&](int c, int4& r0, int4& r1, int4& r2, int4& r3) {
    int ko = c * BK, seg = ko / KH, wi = ko % KH;
    int pb = (seg == 2) ? KH + wi : wi;
    const int4* q = (const int4*)(Bk + (size_t)(ct * 128 + bn) * (2 * KH) + pb + bg);
    r0 = q[0]; r1 = q[1]; r2 = q[2]; r3 = q[3];
  };
  auto loadA_to = [&](int c, int4& r0, int4& r1) {
    int ko = c * BK, seg = ko / KH, wi = ko % KH;
    int pa = ((seg == 1) ? KH : 0) + wi + ag;    // phys short idx in [0, 2*KH)
    if (FUSED) {
      // A row = [hi_l |hi_r | lo_l | lo_r]; hs row = [hi(128) | lo(128)]
      int s4 = pa >> 7;                          // 0:hi_l 1:hi_r 2:lo_l 3:lo_r
      int node = (s4 & 1) ? riS[ar] : liS[ar];
      if (nodesS[ar] >= 0) {
        const int4* q = (const int4*)(hsrc + (size_t)node * 256 + ((s4 >> 1) << 7) + (pa & 127));
        r0 = q[0];
        if (TPR == 4) r1 = q[1];
      } else {
        r0 = make_int4(0, 0, 0, 0);
        if (TPR == 4) r1 = make_int4(0, 0, 0, 0);
      }
    } else {
      const int4* q = (const int4*)(A + (size_t)(row0 + ar) * (2 * KH) + pa);
      r0 = q[0];
      if (TPR == 4) r1 = q[1];
    }
  };
  auto storeA = [&](int b, const int4& r0, const int4& r1) {
    int4* d4 = (int4*)&As[b * ASTR + ar * LDA + ag];
    d4[0] = r0;
    if (TPR == 4) d4[1] = r1;
  };
  auto storeB = [&](int b, const int4& r0, const int4& r1, const int4& r2, const int4& r3) {
    int4* db = (int4*)&Bs[b * BSTR + bn * LDA + bg];
    db[0] = r0; db[1] = r1; db[2] = r2; db[3] = r3;
  };
  auto compute = [&](int b) {
    __builtin_amdgcn_s_setprio(1);
    #pragma unroll
    for (int s = 0; s < 2; ++s) {
      const int ko = s * 32 + oct * 8;
      bf16x8 afr[RF];
      #pragma unroll
      for (int rf = 0; rf < RF; ++rf)
        afr[rf] = *(const bf16x8*)&As[b * ASTR + (wr + rf * 16 + l15) * LDA + ko];
      #pragma unroll
      for (int cf = 0; cf < 4; ++cf) {
        bf16x8 bb = *(const bf16x8*)&Bs[b * BSTR + (wc * 64 + cf * 16 + l15) * LDA + ko];
        #pragma unroll
        for (int rf = 0; rf < RF; ++rf)
          acc[rf][cf] = __builtin_amdgcn_mfma_f32_16x16x32_bf16(afr[rf], bb, acc[rf][cf], 0, 0, 0);
      }
    }
    __builtin_amdgcn_s_setprio(0);
  };

  // ---- main loop (r2 verbatim): dbuf LDS, 2 reg sets, 1 barrier/chunk
  int4 a00, a01, a10, a11;
  int4 b00, b01, b02, b03, b10, b11, b12, b13;
  loadA_to(0, a00, a01); loadB_to(0, b00, b01, b02, b03);
  loadA_to(1, a10, a11); loadB_to(1, b10, b11, b12, b13);
  storeA(0, a00, a01); storeB(0, b00, b01, b02, b03);
  __syncthreads();
  for (int c = 0; c < NCH; c += 2) {
    storeA(1, a10, a11); storeB(1, b10, b11, b12, b13);   // chunk c+1 -> buf1
    if (c + 2 < NCH) { loadA_to(c + 2, a00, a01); loadB_to(c + 2, b00, b01, b02, b03); }
    compute(0);                                           // chunk c from buf0
    __syncthreads();
    if (c + 2 < NCH) { storeA(0, a00, a01); storeB(0, b00, b01, b02, b03); }
    if (c + 3 < NCH) { loadA_to(c + 3, a10, a11); loadB_to(c + 3, b10, b11, b12, b13); }
    compute(1);                                           // chunk c+1 from buf1
    __syncthreads();
  }

  // ---- Epilogue (coalesced via LDS; Bs free after the final barrier)
  if (EPI == 0) {
    short* Ls = Bs;                        // TROWS*128 shorts
    #pragma unroll
    for (int part = 0; part < 2; ++part) {
      __syncthreads();
      #pragma unroll
      for (int rf = 0; rf < RF; ++rf)
        #pragma unroll
        for (int cf = 0; cf < 4; ++cf) {
          int colL = wc * 64 + cf * 16 + l15;
          float bv = bias[kfn * NN + ct * 128 + colL];
          #pragma unroll
          for (int j = 0; j < 4; ++j) {
            int row = wr + rf * 16 + oct * 4 + j;
            float v = fmaxf(acc[rf][cf][j] + bv, 0.f);
            unsigned short hh = f2bf(v);
            unsigned short val = (part == 0) ? hh : f2bf(v - bf2f(hh));
            Ls[row * 128 + colL] = (short)val;
          }
        }
      __syncthreads();
      constexpr int SPT = TROWS / 2;       // shorts per thread (32 or 16)
      constexpr int TPW = 128 / SPT;       // threads per row (4 or 8)
      int row = tid / TPW, sg = (tid % TPW) * SPT;
      const int4* src = (const int4*)&Ls[row * 128 + sg];
      int4* dst = (int4*)&Aout[(size_t)(row0 + row) * (2 * NN) + part * NN + ct * 128 + sg];
      #pragma unroll
      for (int q = 0; q < SPT / 8; ++q) dst[q] = src[q];
    }
  } else if (EPI == 1) {
    float* Lf = (float*)Bs;                // TROWS*64 floats
    #pragma unroll
    for (int h = 0; h < 2; ++h) {
      __syncthreads();
      if (wc == h) {
        #pragma unroll
        for (int rf = 0; rf < RF; ++rf)
          #pragma unroll
          for (int cf = 0; cf < 4; ++cf) {
            int colL = cf * 16 + l15;
            float bv = bias[kfn * 128 + h * 64 + colL];
            #pragma unroll
            for (int j = 0; j < 4; ++j) {
              int row = wr + rf * 16 + oct * 4 + j;
              Lf[row * 64 + colL] = acc[rf][cf][j] + bv;
            }
          }
      }
      __syncthreads();
      constexpr int FPT = TROWS / 4;       // floats per thread (16 or 8)
      constexpr int TPW = 64 / FPT;        // threads per row (4 or 8)
      int row = tid / TPW, off = (tid % TPW) * FPT;
      int node = nodesS[row];
      if (node >= 0) {
        const float4* src = (const float4*)&Lf[row * 64 + off];
        float4* dst = (float4*)&outp[(size_t)node * 128 + h * 64 + off];
        #pragma unroll
        for (int q = 0; q < FPT / 4; ++q) dst[q] = src[q];
      }
    }
  } else {                                 // EPI == 2: split-bf16 hs scatter
    short* Ls = Bs;                        // TROWS*256 shorts
    #pragma unroll
    for (int rf = 0; rf < RF; ++rf)
      #pragma unroll
      for (int cf = 0; cf < 4; ++cf) {
        int colL = wc * 64 + cf * 16 + l15;
        float bv = bias[kfn * 128 + colL];
        #pragma unroll
        for (int j = 0; j < 4; ++j) {
          int row = wr + rf * 16 + oct * 4 + j;
          float v = acc[rf][cf][j] + bv;
          unsigned short hh = f2bf(v);
          Ls[row * 256 + colL]       = (short)hh;
          Ls[row * 256 + 128 + colL] = (short)f2bf(v - bf2f(hh));
        }
      }
    __syncthreads();
    constexpr int SPT = TROWS;             // shorts per thread
    constexpr int TPW = 256 / SPT;         // threads per row
    int row = tid / TPW, sg = (tid % TPW) * SPT;
    int node = nodesS[row];
    if (node >= 0) {
      const int4* src = (const int4*)&Ls[row * 256 + sg];
      int4* dst = (int4*)&Aout[(size_t)node * 256 + sg];
      #pragma unroll
      for (int q = 0; q < SPT / 8; ++q) dst[q] = src[q];
    }
  }
}

// ---------------------------------------------------------------------------
// Cooperative mega-kernel: setup + all 17 GEMM stages with grid.sync()
// between dependent stages. Persistent blocks iterate tiles; no per-stage
// launch/ramp/drain. Tile bodies identical to the split path -> bit-identical.
__global__ __launch_bounds__(256, 2) void mega(P p) {
  __shared__ __align__(16) short As[2 * 64 * 72];
  __shared__ __align__(16) short Bs[2 * 128 * 72];
  __shared__ int nodesS[64], liS[64], riS[64];
  __shared__ int cnt[8], cur[8];

  cg::grid_group grid = cg::this_grid();
  const int bid = blockIdx.x;
  const int NB  = gridDim.x;

  // ---- stage 0: leaf gather + weight prep + fid bucketing (independent)
  for (int u = bid; u < (M * D) / 256; u += NB) leaf_unit(u, p);
  {
    float (*T)[65] = reinterpret_cast<float (*)[65]>(&Bs[0]);   // 16.6 KB alias
    for (int t = bid; t < 768; t += NB) prep_tile(t, p, T);
  }
  if (bid < L + 1) bucket_body(bid, p, cnt, cur);
  __threadfence();
  grid.sync();

  short* hin  = p.hsA;
  short* hout = p.hsB;
  for (int l = 0; l < L; ++l) {
    const int* ord = p.orders + l * PADL;
    const int* fl  = p.nf_fid + l * M;
    for (int t = bid; t < 544; t += NB)         // G1: 136 x-tiles x 4 ct
      gemm_tile<256, 512, 0, 1, 64>(t % 136, t / 136, nullptr, hin,
          p.left_idx + l * M, p.right_idx + l * M, p.B1T, p.b1,
          p.a1s, nullptr, ord, fl, As, Bs, nodesS, liS, riS);
    __threadfence(); grid.sync();
    for (int t = bid; t < 272; t += NB)         // G2: 136 x 2 ct
      gemm_tile<512, 256, 0, 0, 64>(t % 136, t / 136, p.a1s, nullptr,
          nullptr, nullptr, p.B2T, p.b2,
          p.a2s, nullptr, ord, fl, As, Bs, nodesS, liS, riS);
    __threadfence(); grid.sync();
    for (int t = bid; t < 272; t += NB)         // G3: 272 x-tiles (32-row)
      gemm_tile<256, 128, 2, 0, 32>(t, 0, p.a2s, nullptr,
          nullptr, nullptr, p.B3T, p.b3,
          hout, nullptr, ord, fl, As, Bs, nodesS, liS, riS);
    __threadfence(); grid.sync();
    short* tmp = hin; hin = hout; hout = tmp;
  }
  const int* ordG = p.orders + L * PADL;
  for (int t = bid; t < 272; t += NB)           // LG1: 68 x 4 ct
    gemm_tile<256, 512, 0, 1, 64>(t % 68, t / 68, nullptr, hin,
        p.gt_left, p.gt_right, p.BL1T, p.bl1,
        p.a1s, nullptr, ordG, p.lf_fid, As, Bs, nodesS, liS, riS);
  __threadfence(); grid.sync();
  for (int t = bid; t < 136; t += NB)           // LG2: 136 x-tiles (32-row)
    gemm_tile<512, 128, 1, 0, 32>(t, 0, p.a1s, nullptr,
        nullptr, nullptr, p.BL2T, p.bl2,
        nullptr, p.out, ordG, p.lf_fid, As, Bs, nodesS, liS, riS);
}

// ---------------------------------------------------------------------------
// Fallback wrappers (r2 split path) in case cooperative launch is rejected.
__global__ void leaf_k(P p) { leaf_unit(blockIdx.x, p); }
__global__ void bucket_k(P p) {
  __shared__ int cnt[8], cur[8];
  bucket_body(blockIdx.x, p, cnt, cur);
}
__global__ void prep_k(P p) {
  __shared__ float T[64][65];
  prep_tile(blockIdx.x, p, T);
}
template<int KH, int NN, int EPI, int FUSED, int TROWS>
__global__ __launch_bounds__(256, TROWS == 64 ? 2 : 3) void gemm_k(
    const short* A, const short* hsrc, const int* gl, const int* gr,
    const short* BT, const float* bias, short* Aout, float* outp,
    const int* order, const int* fid) {
  __shared__ __align__(16) short As[2 * TROWS * 72];
  __shared__ __align__(16) short Bs[2 * 128 * 72];
  __shared__ int nodesS[TROWS], liS[TROWS], riS[TROWS];
  int bx = xcd_swizzle(blockIdx.x, gridDim.x);
  gemm_tile<KH, NN, EPI, FUSED, TROWS>(bx, blockIdx.y, A, hsrc, gl, gr, BT,
      bias, Aout, outp, order, fid, As, Bs, nodesS, liS, riS);
}

// ---------------------------------------------------------------------------
extern "C" void kernel_launch(void* const* d_in, const int* in_sizes, int n_in,
                              void* d_out, int out_size, void* d_ws, size_t ws_size,
                              hipStream_t stream) {
  const int*   leaf_ids  = (const int*)d_in[0];
  const int*   left_idx  = (const int*)d_in[1];
  const int*   right_idx = (const int*)d_in[2];
  const int*   nf_fid    = (const int*)d_in[3];
  const int*   gt_left   = (const int*)d_in[4];
  const int*   gt_right  = (const int*)d_in[5];
  const int*   lf_fid    = (const int*)d_in[6];
  const float* emb       = (const float*)d_in[7];

  // workspace layout (~54 MB)
  const size_t SZ_H    = (size_t)M * 256 * 2;          // split-bf16 h rows
  const size_t SZ_A1   = (size_t)PADL * 1024 * 2;
  const size_t SZ_A2   = (size_t)PADL * 512 * 2;
  const size_t SZ_B1T  = (size_t)8 * 512 * 512 * 2;
  const size_t SZ_B2T  = (size_t)8 * 256 * 1024 * 2;
  const size_t SZ_B3T  = (size_t)8 * 128 * 512 * 2;
  const size_t SZ_BL1T = (size_t)4 * 512 * 512 * 2;
  const size_t SZ_BL2T = (size_t)4 * 128 * 1024 * 2;

  char* q = (char*)d_ws;
  short* hsA  = (short*)q;  q += SZ_H;
  short* hsB  = (short*)q;  q += SZ_H;
  short* a1s  = (short*)q;  q += SZ_A1;
  short* a2s  = (short*)q;  q += SZ_A2;
  short* B1T  = (short*)q;  q += SZ_B1T;
  short* B2T  = (short*)q;  q += SZ_B2T;
  short* B3T  = (short*)q;  q += SZ_B3T;
  short* BL1T = (short*)q;  q += SZ_BL1T;
  short* BL2T = (short*)q;  q += SZ_BL2T;
  int*   orders = (int*)q;

  P prm;
  prm.leaf_ids = leaf_ids; prm.left_idx = left_idx; prm.right_idx = right_idx;
  prm.nf_fid = nf_fid; prm.gt_left = gt_left; prm.gt_right = gt_right;
  prm.lf_fid = lf_fid; prm.emb = emb;
  prm.W1 = (const float*)d_in[8];  prm.b1 = (const float*)d_in[9];
  prm.W2 = (const float*)d_in[10]; prm.b2 = (const float*)d_in[11];
  prm.W3 = (const float*)d_in[12]; prm.b3 = (const float*)d_in[13];
  prm.Wl1 = (const float*)d_in[14]; prm.bl1 = (const float*)d_in[15];
  prm.Wl2 = (const float*)d_in[16]; prm.bl2 = (const float*)d_in[17];
  prm.out = (float*)d_out;
  prm.hsA = hsA; prm.hsB = hsB; prm.a1s = a1s; prm.a2s = a2s;
  prm.B1T = B1T; prm.B2T = B2T; prm.B3T = B3T; prm.BL1T = BL1T; prm.BL2T = BL2T;
  prm.orders = orders;

  // Cooperative path: grid sized to guaranteed co-residency.
  int maxB = 0;
  hipError_t oe = hipOccupancyMaxActiveBlocksPerMultiprocessor(&maxB, mega, 256, 0);
  int grid = (oe == hipSuccess && maxB >= 1) ? maxB * 256 : 256;
  if (grid > 512) grid = 512;
  void* args[] = { (void*)&prm };
  hipError_t e = hipLaunchCooperativeKernel(mega, dim3(grid), dim3(256), args, 0, stream);
  if (e == hipSuccess) return;

  // ---- fallback: r2 split sequence (known-good 462 us)
  leaf_k<<<(M * D) / 256, 256, 0, stream>>>(prm);
  bucket_k<<<L + 1, 256, 0, stream>>>(prm);
  prep_k<<<768, 256, 0, stream>>>(prm);
  short* hin = hsA;
  short* hout = hsB;
  for (int l = 0; l < L; ++l) {
    const int* ord = orders + l * PADL;
    const int* fl  = nf_fid + l * M;
    gemm_k<256, 512, 0, 1, 64><<<dim3(PADL / 64, 4), 256, 0, stream>>>(
        nullptr, hin, left_idx + l * M, right_idx + l * M,
        B1T, prm.b1, a1s, nullptr, ord, fl);
    gemm_k<512, 256, 0, 0, 64><<<dim3(PADL / 64, 2), 256, 0, stream>>>(
        a1s, nullptr, nullptr, nullptr, B2T, prm.b2, a2s, nullptr, ord, fl);
    gemm_k<256, 128, 2, 0, 32><<<dim3(PADL / 32, 1), 256, 0, stream>>>(
        a2s, nullptr, nullptr, nullptr, B3T, prm.b3, hout, nullptr, ord, fl);
    short* t = hin; hin = hout; hout = t;
  }
  const int* ordG = orders + L * PADL;
  gemm_k<256, 512, 0, 1, 64><<<dim3(PADG / 64, 4), 256, 0, stream>>>(
      nullptr, hin, gt_left, gt_right, BL1T, prm.bl1, a1s, nullptr, ordG, lf_fid);
  gemm_k<512, 128, 1, 0, 32><<<dim3(PADG / 32, 1), 256, 0, stream>>>(
      a1s, nullptr, nullptr, nullptr, BL2T, prm.bl2, nullptr, prm.out, ordG, lf_fid);
}

// Round 9
// 991.765 us; speedup vs baseline: 1.5740x; 1.5740x over previous
//
#include <hip/hip_runtime.h>

// Problem constants
constexpr int D  = 128;
constexpr int M  = 8192;
constexpr int L  = 5;
constexpr int K  = 8;
constexpr int KL = 4;
constexpr int G  = 4096;

constexpr int TB   = 64;            // bucket pad granularity
constexpr int PADL = M + K * TB;    // 8704
constexpr int PADG = G + KL * TB;   // 4352

typedef short bf16x8 __attribute__((ext_vector_type(8)));
typedef float f32x4  __attribute__((ext_vector_type(4)));

__device__ __forceinline__ unsigned short f2bf(float x) {
  union { float f; unsigned int u; } c; c.f = x;
  unsigned int u = c.u + 0x7FFF + ((c.u >> 16) & 1);   // RNE
  return (unsigned short)(u >> 16);
}
__device__ __forceinline__ float bf2f(unsigned short h) {
  union { unsigned int u; float f; } c; c.u = ((unsigned int)h) << 16;
  return c.f;
}

// All pointers bundled.
struct P {
  const int *leaf_ids, *left_idx, *right_idx, *nf_fid, *gt_left, *gt_right, *lf_fid;
  const float *emb, *W1, *b1, *W2, *b2, *W3, *b3, *Wl1, *bl1, *Wl2, *bl2;
  float* out;
  short *hsA, *hsB, *a1s, *a2s, *B1T, *B2T, *B3T, *BL1T, *BL2T;
  int* orders;
  int* bars;                       // 16 inter-stage barrier counters
};

// ---------------------------------------------------------------------------
__device__ __forceinline__ void leaf_unit(int u, const P& p) {
  int idx = u * 256 + threadIdx.x;               // over M*128
  int n = idx >> 7, d = idx & 127;
  float w = p.emb[(size_t)p.leaf_ids[n] * D + d];
  unsigned short hh = f2bf(w);
  p.hsA[n * 256 + d]       = (short)hh;
  p.hsA[n * 256 + 128 + d] = (short)f2bf(w - bf2f(hh));
}

// Weight prep via 64x64 LDS transpose tile (both sides coalesced).
__device__ void prep_tile(int b, const P& p, float (*T)[65]) {
  const float* W; short* BT; int KD, F;
  if      (b < 256) { W = p.W1;  BT = p.B1T;  KD = 256; F = 512; }
  else if (b < 512) { W = p.W2;  BT = p.B2T;  KD = 512; F = 256; b -= 256; }
  else if (b < 576) { W = p.W3;  BT = p.B3T;  KD = 256; F = 128; b -= 512; }
  else if (b < 704) { W = p.Wl1; BT = p.BL1T; KD = 256; F = 512; b -= 576; }
  else              { W = p.Wl2; BT = p.BL2T; KD = 512; F = 128; b -= 704; }
  const int ntd = KD >> 6, ntf = F >> 6;
  const int k  = b / (ntd * ntf), rem = b % (ntd * ntf);
  const int d0 = (rem / ntf) << 6, f0 = (rem % ntf) << 6;
  const int tid = threadIdx.x, ln = tid & 63, w4 = tid >> 6;
  #pragma unroll
  for (int i = 0; i < 16; ++i) {                 // read rows d, coalesced over f
    int d = w4 * 16 + i;
    T[ln][d] = W[((size_t)k * KD + d0 + d) * F + f0 + ln];
  }
  __syncthreads();
  #pragma unroll
  for (int i = 0; i < 16; ++i) {                 // write rows f, coalesced over d
    int f = w4 * 16 + i;
    float w = T[f][ln];
    unsigned short hi = f2bf(w);
    unsigned short lo = f2bf(w - bf2f(hi));
    size_t base = ((size_t)k * F + f0 + f) * (2 * KD) + d0;
    BT[base + ln]      = (short)hi;
    BT[base + KD + ln] = (short)lo;
  }
}

// Bucket node indices by fid, padded to 64; pad = -1.
__device__ void bucket_body(int b, const P& p, int* cnt, int* cur) {
  const int* fid; int N, Kf, cap; int* outp;
  if (b < L) { fid = p.nf_fid + b * M; N = M; Kf = K;  cap = PADL; outp = p.orders + b * PADL; }
  else       { fid = p.lf_fid;         N = G; Kf = KL; cap = PADG; outp = p.orders + L * PADL; }
  int tid = threadIdx.x;
  if (tid < Kf) cnt[tid] = 0;
  __syncthreads();
  for (int i = tid; i < N; i += 256) atomicAdd(&cnt[fid[i]], 1);
  __syncthreads();
  if (tid == 0) {
    int off = 0;
    for (int k = 0; k < Kf; ++k) { cur[k] = off; off += ((cnt[k] + TB - 1) / TB) * TB; }
  }
  __syncthreads();
  for (int i = tid; i < cap; i += 256) outp[i] = -1;
  __syncthreads();
  for (int i = tid; i < N; i += 256) {
    int kk = fid[i];
    int pos = atomicAdd(&cur[kk], 1);
    outp[pos] = i;
  }
}

// ---------------------------------------------------------------------------
// One GEMM tile: r2's known-best body (plain __syncthreads, dbuf LDS,
// 2 register prefetch sets, 1 barrier/chunk). Proven bit-exact through the
// r8 mega path. Split-bf16 logical K' = 3*KH: A segs {hi,lo,hi}, B {hi,hi,lo}.
template<int KH, int NN, int EPI, int FUSED, int TROWS>
__device__ void gemm_tile(
    int bx, int ct,
    const short* __restrict__ A, const short* __restrict__ hsrc,
    const int* __restrict__ gl, const int* __restrict__ gr,
    const short* __restrict__ BT, const float* __restrict__ bias,
    short* __restrict__ Aout, float* __restrict__ outp,
    const int* __restrict__ order, const int* __restrict__ fid,
    short* As, short* Bs, int* nodesS, int* liS, int* riS) {
  constexpr int BK   = 64;
  constexpr int NCH  = 3 * KH / BK;       // 12 or 24 (even)
  constexpr int LDA  = 72;                // 2-way bank alias (free)
  constexpr int ASTR = TROWS * LDA;
  constexpr int BSTR = 128 * LDA;
  constexpr int RF   = TROWS / 32;        // row frags per wave: 2 or 1
  constexpr int TPR  = 256 / TROWS;       // A-staging threads per row: 4 or 8

  const int tid  = threadIdx.x;
  const int row0 = bx * TROWS;

  __syncthreads();                        // LDS reuse guard (prev tile/stage)
  if (tid < TROWS) {
    int node = order[row0 + tid];
    nodesS[tid] = node;
    if (FUSED) {
      liS[tid] = node >= 0 ? gl[node] : 0;
      riS[tid] = node >= 0 ? gr[node] : 0;
    }
  }
  __syncthreads();
  if (nodesS[0] < 0) return;              // fully-padded tile (uniform)
  const int kfn = fid[nodesS[0]];
  const short* __restrict__ Bk = BT + (size_t)kfn * NN * (2 * KH);

  const int lane = tid & 63, wave = tid >> 6;
  const int wr = (wave >> 1) * (TROWS / 2);   // 2x2 waves
  const int wc = wave & 1;
  const int l15 = lane & 15, oct = lane >> 4;

  const int ar = tid / TPR;                   // A staging row [0,TROWS)
  const int ag = (tid % TPR) * (BK / TPR);    // A short offset (16 or 8)
  const int bn = tid >> 1;                    // B staging col-row [0,128)
  const int bg = (tid & 1) * 32;              // B short offset

  f32x4 acc[RF][4];
  #pragma unroll
  for (int i = 0; i < RF; ++i)
    #pragma unroll
    for (int j = 0; j < 4; ++j) acc[i][j] = (f32x4)0.f;

  auto loadB_to = [&](int c, int4& r0, int4& r1, int4& r2, int4& r3) {
    int ko = c * BK, seg = ko / KH, wi = ko % KH;
    int pb = (seg == 2) ? KH + wi : wi;
    const int4* q = (const int4*)(Bk + (size_t)(ct * 128 + bn) * (2 * KH) + pb + bg);
    r0 = q[0]; r1 = q[1]; r2 = q[2]; r3 = q[3];
  };
  auto loadA_to = [&](int c, int4& r0, int4& r1) {
    int ko = c * BK, seg = ko / KH, wi = ko % KH;
    int pa = ((seg == 1) ? KH : 0) + wi + ag;    // phys short idx in [0, 2*KH)
    if (FUSED) {
      int s4 = pa >> 7;                          // 0:hi_l 1:hi_r 2:lo_l 3:lo_r
      int node = (s4 & 1) ? riS[ar] : liS[ar];
      if (nodesS[ar] >= 0) {
        const int4* q = (const int4*)(hsrc + (size_t)node * 256 + ((s4 >> 1) << 7) + (pa & 127));
        r0 = q[0];
        if (TPR == 4) r1 = q[1];
      } else {
        r0 = make_int4(0, 0, 0, 0);
        if (TPR == 4) r1 = make_int4(0, 0, 0, 0);
      }
    } else {
      const int4* q = (const int4*)(A + (size_t)(row0 + ar) * (2 * KH) + pa);
      r0 = q[0];
      if (TPR == 4) r1 = q[1];
    }
  };
  auto storeA = [&](int b, const int4& r0, const int4& r1) {
    int4* d4 = (int4*)&As[b * ASTR + ar * LDA + ag];
    d4[0] = r0;
    if (TPR == 4) d4[1] = r1;
  };
  auto storeB = [&](int b, const int4& r0, const int4& r1, const int4& r2, const int4& r3) {
    int4* db = (int4*)&Bs[b * BSTR + bn * LDA + bg];
    db[0] = r0; db[1] = r1; db[2] = r2; db[3] = r3;
  };
  auto compute = [&](int b) {
    __builtin_amdgcn_s_setprio(1);
    #pragma unroll
    for (int s = 0; s < 2; ++s) {
      const int ko = s * 32 + oct * 8;
      bf16x8 afr[RF];
      #pragma unroll
      for (int rf = 0; rf < RF; ++rf)
        afr[rf] = *(const bf16x8*)&As[b * ASTR + (wr + rf * 16 + l15) * LDA + ko];
      #pragma unroll
      for (int cf = 0; cf < 4; ++cf) {
        bf16x8 bb = *(const bf16x8*)&Bs[b * BSTR + (wc * 64 + cf * 16 + l15) * LDA + ko];
        #pragma unroll
        for (int rf = 0; rf < RF; ++rf)
          acc[rf][cf] = __builtin_amdgcn_mfma_f32_16x16x32_bf16(afr[rf], bb, acc[rf][cf], 0, 0, 0);
      }
    }
    __builtin_amdgcn_s_setprio(0);
  };

  int4 a00, a01, a10, a11;
  int4 b00, b01, b02, b03, b10, b11, b12, b13;
  loadA_to(0, a00, a01); loadB_to(0, b00, b01, b02, b03);
  loadA_to(1, a10, a11); loadB_to(1, b10, b11, b12, b13);
  storeA(0, a00, a01); storeB(0, b00, b01, b02, b03);
  __syncthreads();
  for (int c = 0; c < NCH; c += 2) {
    storeA(1, a10, a11); storeB(1, b10, b11, b12, b13);   // chunk c+1 -> buf1
    if (c + 2 < NCH) { loadA_to(c + 2, a00, a01); loadB_to(c + 2, b00, b01, b02, b03); }
    compute(0);                                           // chunk c from buf0
    __syncthreads();
    if (c + 2 < NCH) { storeA(0, a00, a01); storeB(0, b00, b01, b02, b03); }
    if (c + 3 < NCH) { loadA_to(c + 3, a10, a11); loadB_to(c + 3, b10, b11, b12, b13); }
    compute(1);                                           // chunk c+1 from buf1
    __syncthreads();
  }

  // ---- Epilogue (coalesced via LDS; Bs free after the final barrier)
  if (EPI == 0) {
    short* Ls = Bs;                        // TROWS*128 shorts
    #pragma unroll
    for (int part = 0; part < 2; ++part) {
      __syncthreads();
      #pragma unroll
      for (int rf = 0; rf < RF; ++rf)
        #pragma unroll
        for (int cf = 0; cf < 4; ++cf) {
          int colL = wc * 64 + cf * 16 + l15;
          float bv = bias[kfn * NN + ct * 128 + colL];
          #pragma unroll
          for (int j = 0; j < 4; ++j) {
            int row = wr + rf * 16 + oct * 4 + j;
            float v = fmaxf(acc[rf][cf][j] + bv, 0.f);
            unsigned short hh = f2bf(v);
            unsigned short val = (part == 0) ? hh : f2bf(v - bf2f(hh));
            Ls[row * 128 + colL] = (short)val;
          }
        }
      __syncthreads();
      constexpr int SPT = TROWS / 2;       // shorts per thread (32 or 16)
      constexpr int TPW = 128 / SPT;       // threads per row (4 or 8)
      int row = tid / TPW, sg = (tid % TPW) * SPT;
      const int4* src = (const int4*)&Ls[row * 128 + sg];
      int4* dst = (int4*)&Aout[(size_t)(row0 + row) * (2 * NN) + part * NN + ct * 128 + sg];
      #pragma unroll
      for (int q = 0; q < SPT / 8; ++q) dst[q] = src[q];
    }
  } else if (EPI == 1) {
    float* Lf = (float*)Bs;                // TROWS*64 floats
    #pragma unroll
    for (int h = 0; h < 2; ++h) {
      __syncthreads();
      if (wc == h) {
        #pragma unroll
        for (int rf = 0; rf < RF; ++rf)
          #pragma unroll
          for (int cf = 0; cf < 4; ++cf) {
            int colL = cf * 16 + l15;
            float bv = bias[kfn * 128 + h * 64 + colL];
            #pragma unroll
            for (int j = 0; j < 4; ++j) {
              int row = wr + rf * 16 + oct * 4 + j;
              Lf[row * 64 + colL] = acc[rf][cf][j] + bv;
            }
          }
      }
      __syncthreads();
      constexpr int FPT = TROWS / 4;       // floats per thread (16 or 8)
      constexpr int TPW = 64 / FPT;        // threads per row (4 or 8)
      int row = tid / TPW, off = (tid % TPW) * FPT;
      int node = nodesS[row];
      if (node >= 0) {
        const float4* src = (const float4*)&Lf[row * 64 + off];
        float4* dst = (float4*)&outp[(size_t)node * 128 + h * 64 + off];
        #pragma unroll
        for (int q = 0; q < FPT / 4; ++q) dst[q] = src[q];
      }
    }
  } else {                                 // EPI == 2: split-bf16 hs scatter
    short* Ls = Bs;                        // TROWS*256 shorts
    #pragma unroll
    for (int rf = 0; rf < RF; ++rf)
      #pragma unroll
      for (int cf = 0; cf < 4; ++cf) {
        int colL = wc * 64 + cf * 16 + l15;
        float bv = bias[kfn * 128 + colL];
        #pragma unroll
        for (int j = 0; j < 4; ++j) {
          int row = wr + rf * 16 + oct * 4 + j;
          float v = acc[rf][cf][j] + bv;
          unsigned short hh = f2bf(v);
          Ls[row * 256 + colL]       = (short)hh;
          Ls[row * 256 + 128 + colL] = (short)f2bf(v - bf2f(hh));
        }
      }
    __syncthreads();
    constexpr int SPT = TROWS;             // shorts per thread
    constexpr int TPW = 256 / SPT;         // threads per row
    int row = tid / TPW, sg = (tid % TPW) * SPT;
    int node = nodesS[row];
    if (node >= 0) {
      const int4* src = (const int4*)&Ls[row * 256 + sg];
      int4* dst = (int4*)&Aout[(size_t)node * 256 + sg];
      #pragma unroll
      for (int q = 0; q < SPT / 8; ++q) dst[q] = src[q];
    }
  }
}

// ---------------------------------------------------------------------------
// Setup kernel: leaf gather + weight prep + bucketing + barrier zeroing.
__global__ __launch_bounds__(256) void setup_k(P p) {
  __shared__ float T[64][65];
  __shared__ int cnt[8], cur[8];
  int b = blockIdx.x;
  if (b < 4096) {
    leaf_unit(b, p);
  } else if (b < 4864) {
    prep_tile(b - 4096, p, T);
  } else {
    if (b == 4864 && threadIdx.x < 32) p.bars[threadIdx.x] = 0;
    bucket_body(b - 4864, p, cnt, cur);
  }
}

// ---------------------------------------------------------------------------
// Persistent GEMM-chain kernel. 272 blocks, __launch_bounds__(256,2) =>
// LDS 56KB <= 80KB and VGPR <= 128 => capacity 512 blocks => all 272
// co-resident by construction (plain launch, graph-capture safe).
// Inter-stage sync: one device-scope atomicAdd + relaxed agent-scope spin
// (s_sleep backoff) + __threadfence release/acquire -- replaces the ~120us
// cg::grid.sync measured in r8.
__global__ __launch_bounds__(256, 2) void mega2(P p) {
  __shared__ __align__(16) short As[2 * 64 * 72];
  __shared__ __align__(16) short Bs[2 * 128 * 72];
  __shared__ int nodesS[64], liS[64], riS[64];

  const int bid = blockIdx.x;
  const int NB  = gridDim.x;

  auto gbar = [&](int s) {
    __syncthreads();
    if (threadIdx.x == 0) {
      __threadfence();                      // release: flush my stage writes
      __hip_atomic_fetch_add(&p.bars[s], 1, __ATOMIC_RELEASE, __HIP_MEMORY_SCOPE_AGENT);
      while (__hip_atomic_load(&p.bars[s], __ATOMIC_RELAXED, __HIP_MEMORY_SCOPE_AGENT) < NB)
        __builtin_amdgcn_s_sleep(1);
      __threadfence();                      // acquire: invalidate stale lines
    }
    __syncthreads();
  };

  short* hin  = p.hsA;
  short* hout = p.hsB;
  int s = 0;
  for (int l = 0; l < L; ++l) {
    const int* ord = p.orders + l * PADL;
    const int* fl  = p.nf_fid + l * M;
    for (int t = bid; t < 544; t += NB)         // G1: 136 x-tiles x 4 ct
      gemm_tile<256, 512, 0, 1, 64>(t % 136, t / 136, nullptr, hin,
          p.left_idx + l * M, p.right_idx + l * M, p.B1T, p.b1,
          p.a1s, nullptr, ord, fl, As, Bs, nodesS, liS, riS);
    gbar(s++);
    for (int t = bid; t < 272; t += NB)         // G2: 136 x 2 ct
      gemm_tile<512, 256, 0, 0, 64>(t % 136, t / 136, p.a1s, nullptr,
          nullptr, nullptr, p.B2T, p.b2,
          p.a2s, nullptr, ord, fl, As, Bs, nodesS, liS, riS);
    gbar(s++);
    for (int t = bid; t < 272; t += NB)         // G3: 272 x-tiles (32-row)
      gemm_tile<256, 128, 2, 0, 32>(t, 0, p.a2s, nullptr,
          nullptr, nullptr, p.B3T, p.b3,
          hout, nullptr, ord, fl, As, Bs, nodesS, liS, riS);
    gbar(s++);
    short* tmp = hin; hin = hout; hout = tmp;
  }
  const int* ordG = p.orders + L * PADL;
  for (int t = bid; t < 272; t += NB)           // LG1: 68 x 4 ct
    gemm_tile<256, 512, 0, 1, 64>(t % 68, t / 68, nullptr, hin,
        p.gt_left, p.gt_right, p.BL1T, p.bl1,
        p.a1s, nullptr, ordG, p.lf_fid, As, Bs, nodesS, liS, riS);
  gbar(s++);                                    // s == 16 barriers total
  for (int t = bid; t < 136; t += NB)           // LG2: 136 x-tiles (32-row)
    gemm_tile<512, 128, 1, 0, 32>(t, 0, p.a1s, nullptr,
        nullptr, nullptr, p.BL2T, p.bl2,
        nullptr, p.out, ordG, p.lf_fid, As, Bs, nodesS, liS, riS);
}

// ---------------------------------------------------------------------------
extern "C" void kernel_launch(void* const* d_in, const int* in_sizes, int n_in,
                              void* d_out, int out_size, void* d_ws, size_t ws_size,
                              hipStream_t stream) {
  // workspace layout (~54 MB)
  const size_t SZ_H    = (size_t)M * 256 * 2;          // split-bf16 h rows
  const size_t SZ_A1   = (size_t)PADL * 1024 * 2;
  const size_t SZ_A2   = (size_t)PADL * 512 * 2;
  const size_t SZ_B1T  = (size_t)8 * 512 * 512 * 2;
  const size_t SZ_B2T  = (size_t)8 * 256 * 1024 * 2;
  const size_t SZ_B3T  = (size_t)8 * 128 * 512 * 2;
  const size_t SZ_BL1T = (size_t)4 * 512 * 512 * 2;
  const size_t SZ_BL2T = (size_t)4 * 128 * 1024 * 2;

  char* q = (char*)d_ws;
  short* hsA  = (short*)q;  q += SZ_H;
  short* hsB  = (short*)q;  q += SZ_H;
  short* a1s  = (short*)q;  q += SZ_A1;
  short* a2s  = (short*)q;  q += SZ_A2;
  short* B1T  = (short*)q;  q += SZ_B1T;
  short* B2T  = (short*)q;  q += SZ_B2T;
  short* B3T  = (short*)q;  q += SZ_B3T;
  short* BL1T = (short*)q;  q += SZ_BL1T;
  short* BL2T = (short*)q;  q += SZ_BL2T;
  int*   orders = (int*)q;
  int*   bars   = orders + 6 * PADL;            // past all order tables

  P prm;
  prm.leaf_ids  = (const int*)d_in[0];
  prm.left_idx  = (const int*)d_in[1];
  prm.right_idx = (const int*)d_in[2];
  prm.nf_fid    = (const int*)d_in[3];
  prm.gt_left   = (const int*)d_in[4];
  prm.gt_right  = (const int*)d_in[5];
  prm.lf_fid    = (const int*)d_in[6];
  prm.emb       = (const float*)d_in[7];
  prm.W1 = (const float*)d_in[8];  prm.b1 = (const float*)d_in[9];
  prm.W2 = (const float*)d_in[10]; prm.b2 = (const float*)d_in[11];
  prm.W3 = (const float*)d_in[12]; prm.b3 = (const float*)d_in[13];
  prm.Wl1 = (const float*)d_in[14]; prm.bl1 = (const float*)d_in[15];
  prm.Wl2 = (const float*)d_in[16]; prm.bl2 = (const float*)d_in[17];
  prm.out = (float*)d_out;
  prm.hsA = hsA; prm.hsB = hsB; prm.a1s = a1s; prm.a2s = a2s;
  prm.B1T = B1T; prm.B2T = B2T; prm.B3T = B3T; prm.BL1T = BL1T; prm.BL2T = BL2T;
  prm.orders = orders; prm.bars = bars;

  setup_k<<<4870, 256, 0, stream>>>(prm);       // leaf + prep + bucket + bars
  mega2<<<272, 256, 0, stream>>>(prm);          // full GEMM chain, 16 barriers
}

// Round 10
// 628.993 us; speedup vs baseline: 2.4818x; 1.5767x over previous
//
#include <hip/hip_runtime.h>

// Problem constants
constexpr int D  = 128;
constexpr int M  = 8192;
constexpr int L  = 5;
constexpr int K  = 8;
constexpr int KL = 4;
constexpr int G  = 4096;

constexpr int TB   = 64;            // bucket pad granularity
constexpr int PADL = M + K * TB;    // 8704
constexpr int PADG = G + KL * TB;   // 4352

typedef short bf16x8 __attribute__((ext_vector_type(8)));
typedef float f32x4  __attribute__((ext_vector_type(4)));

__device__ __forceinline__ unsigned short f2bf(float x) {
  union { float f; unsigned int u; } c; c.f = x;
  unsigned int u = c.u + 0x7FFF + ((c.u >> 16) & 1);   // RNE
  return (unsigned short)(u >> 16);
}
__device__ __forceinline__ float bf2f(unsigned short h) {
  union { unsigned int u; float f; } c; c.u = ((unsigned int)h) << 16;
  return c.f;
}

// Bijective XCD-chunking swizzle (m204).
__device__ __forceinline__ int xcd_swizzle(int b, int n) {
  int q = n >> 3, r = n & 7, xcd = b & 7, off = b >> 3;
  return (xcd < r ? xcd * (q + 1) : r * (q + 1) + (xcd - r) * q) + off;
}

// All pointers bundled.
struct P {
  const int *leaf_ids, *left_idx, *right_idx, *nf_fid, *gt_left, *gt_right, *lf_fid;
  const float *emb, *W1, *b1, *W2, *b2, *W3, *b3, *Wl1, *bl1, *Wl2, *bl2;
  float* out;
  short *hsA, *hsB, *a1s, *a2s, *B1T, *B2T, *B3T, *BL1T, *BL2T;
  int* orders;
};

// ---------------------------------------------------------------------------
__device__ __forceinline__ void leaf_unit(int u, const P& p) {
  int idx = u * 256 + threadIdx.x;               // over M*128
  int n = idx >> 7, d = idx & 127;
  float w = p.emb[(size_t)p.leaf_ids[n] * D + d];
  unsigned short hh = f2bf(w);
  p.hsA[n * 256 + d]       = (short)hh;
  p.hsA[n * 256 + 128 + d] = (short)f2bf(w - bf2f(hh));
}

// Weight prep via 64x64 LDS transpose tile (both sides coalesced).
__device__ void prep_tile(int b, const P& p, float (*T)[65]) {
  const float* W; short* BT; int KD, F;
  if      (b < 256) { W = p.W1;  BT = p.B1T;  KD = 256; F = 512; }
  else if (b < 512) { W = p.W2;  BT = p.B2T;  KD = 512; F = 256; b -= 256; }
  else if (b < 576) { W = p.W3;  BT = p.B3T;  KD = 256; F = 128; b -= 512; }
  else if (b < 704) { W = p.Wl1; BT = p.BL1T; KD = 256; F = 512; b -= 576; }
  else              { W = p.Wl2; BT = p.BL2T; KD = 512; F = 128; b -= 704; }
  const int ntd = KD >> 6, ntf = F >> 6;
  const int k  = b / (ntd * ntf), rem = b % (ntd * ntf);
  const int d0 = (rem / ntf) << 6, f0 = (rem % ntf) << 6;
  const int tid = threadIdx.x, ln = tid & 63, w4 = tid >> 6;
  #pragma unroll
  for (int i = 0; i < 16; ++i) {                 // read rows d, coalesced over f
    int d = w4 * 16 + i;
    T[ln][d] = W[((size_t)k * KD + d0 + d) * F + f0 + ln];
  }
  __syncthreads();
  #pragma unroll
  for (int i = 0; i < 16; ++i) {                 // write rows f, coalesced over d
    int f = w4 * 16 + i;
    float w = T[f][ln];
    unsigned short hi = f2bf(w);
    unsigned short lo = f2bf(w - bf2f(hi));
    size_t base = ((size_t)k * F + f0 + f) * (2 * KD) + d0;
    BT[base + ln]      = (short)hi;
    BT[base + KD + ln] = (short)lo;
  }
}

// Bucket node indices by fid, padded to 64; pad = -1.
__device__ void bucket_body(int b, const P& p, int* cnt, int* cur) {
  const int* fid; int N, Kf, cap; int* outp;
  if (b < L) { fid = p.nf_fid + b * M; N = M; Kf = K;  cap = PADL; outp = p.orders + b * PADL; }
  else       { fid = p.lf_fid;         N = G; Kf = KL; cap = PADG; outp = p.orders + L * PADL; }
  int tid = threadIdx.x;
  if (tid < Kf) cnt[tid] = 0;
  __syncthreads();
  for (int i = tid; i < N; i += 256) atomicAdd(&cnt[fid[i]], 1);
  __syncthreads();
  if (tid == 0) {
    int off = 0;
    for (int k = 0; k < Kf; ++k) { cur[k] = off; off += ((cnt[k] + TB - 1) / TB) * TB; }
  }
  __syncthreads();
  for (int i = tid; i < cap; i += 256) outp[i] = -1;
  __syncthreads();
  for (int i = tid; i < N; i += 256) {
    int kk = fid[i];
    int pos = atomicAdd(&cur[kk], 1);
    outp[pos] = i;
  }
}

// ---------------------------------------------------------------------------
// One GEMM tile: r2's known-best body (plain __syncthreads, dbuf LDS,
// 2 register prefetch sets, 1 barrier/chunk). Bit-exact proven (r8/r9).
// Split-bf16 logical K' = 3*KH: A segs {hi,lo,hi}, B segs {hi,hi,lo}.
// Entry __syncthreads guards LDS reuse AND (via its vmcnt drain) orders the
// previous tile's global epilogue writes before this tile's A reads --
// that same-block RAW is what makes barrier-free level fusion legal.
template<int KH, int NN, int EPI, int FUSED, int TROWS>
__device__ void gemm_tile(
    int bx, int ct,
    const short* __restrict__ A, const short* __restrict__ hsrc,
    const int* __restrict__ gl, const int* __restrict__ gr,
    const short* __restrict__ BT, const float* __restrict__ bias,
    short* __restrict__ Aout, float* __restrict__ outp,
    const int* __restrict__ order, const int* __restrict__ fid,
    short* As, short* Bs, int* nodesS, int* liS, int* riS) {
  constexpr int BK   = 64;
  constexpr int NCH  = 3 * KH / BK;       // 12 or 24 (even)
  constexpr int LDA  = 72;                // 2-way bank alias (free)
  constexpr int ASTR = TROWS * LDA;
  constexpr int BSTR = 128 * LDA;
  constexpr int RF   = TROWS / 32;        // row frags per wave: 2 or 1
  constexpr int TPR  = 256 / TROWS;       // A-staging threads per row: 4 or 8

  const int tid  = threadIdx.x;
  const int row0 = bx * TROWS;

  __syncthreads();                        // LDS reuse guard + RAW drain
  if (tid < TROWS) {
    int node = order[row0 + tid];
    nodesS[tid] = node;
    if (FUSED) {
      liS[tid] = node >= 0 ? gl[node] : 0;
      riS[tid] = node >= 0 ? gr[node] : 0;
    }
  }
  __syncthreads();
  if (nodesS[0] < 0) return;              // fully-padded tile (uniform)
  const int kfn = fid[nodesS[0]];
  const short* __restrict__ Bk = BT + (size_t)kfn * NN * (2 * KH);

  const int lane = tid & 63, wave = tid >> 6;
  const int wr = (wave >> 1) * (TROWS / 2);   // 2x2 waves
  const int wc = wave & 1;
  const int l15 = lane & 15, oct = lane >> 4;

  const int ar = tid / TPR;                   // A staging row [0,TROWS)
  const int ag = (tid % TPR) * (BK / TPR);    // A short offset (16 or 8)
  const int bn = tid >> 1;                    // B staging col-row [0,128)
  const int bg = (tid & 1) * 32;              // B short offset

  f32x4 acc[RF][4];
  #pragma unroll
  for (int i = 0; i < RF; ++i)
    #pragma unroll
    for (int j = 0; j < 4; ++j) acc[i][j] = (f32x4)0.f;

  auto loadB_to = [&](int c, int4& r0, int4& r1, int4& r2, int4& r3) {
    int ko = c * BK, seg = ko / KH, wi = ko % KH;
    int pb = (seg == 2) ? KH + wi : wi;
    const int4* q = (const int4*)(Bk + (size_t)(ct * 128 + bn) * (2 * KH) + pb + bg);
    r0 = q[0]; r1 = q[1]; r2 = q[2]; r3 = q[3];
  };
  auto loadA_to = [&](int c, int4& r0, int4& r1) {
    int ko = c * BK, seg = ko / KH, wi = ko % KH;
    int pa = ((seg == 1) ? KH : 0) + wi + ag;    // phys short idx in [0, 2*KH)
    if (FUSED) {
      int s4 = pa >> 7;                          // 0:hi_l 1:hi_r 2:lo_l 3:lo_r
      int node = (s4 & 1) ? riS[ar] : liS[ar];
      if (nodesS[ar] >= 0) {
        const int4* q = (const int4*)(hsrc + (size_t)node * 256 + ((s4 >> 1) << 7) + (pa & 127));
        r0 = q[0];
        if (TPR == 4) r1 = q[1];
      } else {
        r0 = make_int4(0, 0, 0, 0);
        if (TPR == 4) r1 = make_int4(0, 0, 0, 0);
      }
    } else {
      const int4* q = (const int4*)(A + (size_t)(row0 + ar) * (2 * KH) + pa);
      r0 = q[0];
      if (TPR == 4) r1 = q[1];
    }
  };
  auto storeA = [&](int b, const int4& r0, const int4& r1) {
    int4* d4 = (int4*)&As[b * ASTR + ar * LDA + ag];
    d4[0] = r0;
    if (TPR == 4) d4[1] = r1;
  };
  auto storeB = [&](int b, const int4& r0, const int4& r1, const int4& r2, const int4& r3) {
    int4* db = (int4*)&Bs[b * BSTR + bn * LDA + bg];
    db[0] = r0; db[1] = r1; db[2] = r2; db[3] = r3;
  };
  auto compute = [&](int b) {
    __builtin_amdgcn_s_setprio(1);
    #pragma unroll
    for (int s = 0; s < 2; ++s) {
      const int ko = s * 32 + oct * 8;
      bf16x8 afr[RF];
      #pragma unroll
      for (int rf = 0; rf < RF; ++rf)
        afr[rf] = *(const bf16x8*)&As[b * ASTR + (wr + rf * 16 + l15) * LDA + ko];
      #pragma unroll
      for (int cf = 0; cf < 4; ++cf) {
        bf16x8 bb = *(const bf16x8*)&Bs[b * BSTR + (wc * 64 + cf * 16 + l15) * LDA + ko];
        #pragma unroll
        for (int rf = 0; rf < RF; ++rf)
          acc[rf][cf] = __builtin_amdgcn_mfma_f32_16x16x32_bf16(afr[rf], bb, acc[rf][cf], 0, 0, 0);
      }
    }
    __builtin_amdgcn_s_setprio(0);
  };

  int4 a00, a01, a10, a11;
  int4 b00, b01, b02, b03, b10, b11, b12, b13;
  loadA_to(0, a00, a01); loadB_to(0, b00, b01, b02, b03);
  loadA_to(1, a10, a11); loadB_to(1, b10, b11, b12, b13);
  storeA(0, a00, a01); storeB(0, b00, b01, b02, b03);
  __syncthreads();
  for (int c = 0; c < NCH; c += 2) {
    storeA(1, a10, a11); storeB(1, b10, b11, b12, b13);   // chunk c+1 -> buf1
    if (c + 2 < NCH) { loadA_to(c + 2, a00, a01); loadB_to(c + 2, b00, b01, b02, b03); }
    compute(0);                                           // chunk c from buf0
    __syncthreads();
    if (c + 2 < NCH) { storeA(0, a00, a01); storeB(0, b00, b01, b02, b03); }
    if (c + 3 < NCH) { loadA_to(c + 3, a10, a11); loadB_to(c + 3, b10, b11, b12, b13); }
    compute(1);                                           // chunk c+1 from buf1
    __syncthreads();
  }

  // ---- Epilogue (coalesced via LDS; Bs free after the final barrier)
  if (EPI == 0) {
    short* Ls = Bs;                        // TROWS*128 shorts
    #pragma unroll
    for (int part = 0; part < 2; ++part) {
      __syncthreads();
      #pragma unroll
      for (int rf = 0; rf < RF; ++rf)
        #pragma unroll
        for (int cf = 0; cf < 4; ++cf) {
          int colL = wc * 64 + cf * 16 + l15;
          float bv = bias[kfn * NN + ct * 128 + colL];
          #pragma unroll
          for (int j = 0; j < 4; ++j) {
            int row = wr + rf * 16 + oct * 4 + j;
            float v = fmaxf(acc[rf][cf][j] + bv, 0.f);
            unsigned short hh = f2bf(v);
            unsigned short val = (part == 0) ? hh : f2bf(v - bf2f(hh));
            Ls[row * 128 + colL] = (short)val;
          }
        }
      __syncthreads();
      constexpr int SPT = TROWS / 2;       // shorts per thread (32 or 16)
      constexpr int TPW = 128 / SPT;       // threads per row (4 or 8)
      int row = tid / TPW, sg = (tid % TPW) * SPT;
      const int4* src = (const int4*)&Ls[row * 128 + sg];
      int4* dst = (int4*)&Aout[(size_t)(row0 + row) * (2 * NN) + part * NN + ct * 128 + sg];
      #pragma unroll
      for (int q = 0; q < SPT / 8; ++q) dst[q] = src[q];
    }
  } else if (EPI == 1) {
    float* Lf = (float*)Bs;                // TROWS*64 floats
    #pragma unroll
    for (int h = 0; h < 2; ++h) {
      __syncthreads();
      if (wc == h) {
        #pragma unroll
        for (int rf = 0; rf < RF; ++rf)
          #pragma unroll
          for (int cf = 0; cf < 4; ++cf) {
            int colL = cf * 16 + l15;
            float bv = bias[kfn * 128 + h * 64 + colL];
            #pragma unroll
            for (int j = 0; j < 4; ++j) {
              int row = wr + rf * 16 + oct * 4 + j;
              Lf[row * 64 + colL] = acc[rf][cf][j] + bv;
            }
          }
      }
      __syncthreads();
      constexpr int FPT = TROWS / 4;       // floats per thread (16 or 8)
      constexpr int TPW = 64 / FPT;        // threads per row (4 or 8)
      int row = tid / TPW, off = (tid % TPW) * FPT;
      int node = nodesS[row];
      if (node >= 0) {
        const float4* src = (const float4*)&Lf[row * 64 + off];
        float4* dst = (float4*)&outp[(size_t)node * 128 + h * 64 + off];
        #pragma unroll
        for (int q = 0; q < FPT / 4; ++q) dst[q] = src[q];
      }
    }
  } else {                                 // EPI == 2: split-bf16 hs scatter
    short* Ls = Bs;                        // TROWS*256 shorts
    #pragma unroll
    for (int rf = 0; rf < RF; ++rf)
      #pragma unroll
      for (int cf = 0; cf < 4; ++cf) {
        int colL = wc * 64 + cf * 16 + l15;
        float bv = bias[kfn * 128 + colL];
        #pragma unroll
        for (int j = 0; j < 4; ++j) {
          int row = wr + rf * 16 + oct * 4 + j;
          float v = acc[rf][cf][j] + bv;
          unsigned short hh = f2bf(v);
          Ls[row * 256 + colL]       = (short)hh;
          Ls[row * 256 + 128 + colL] = (short)f2bf(v - bf2f(hh));
        }
      }
    __syncthreads();
    constexpr int SPT = TROWS;             // shorts per thread
    constexpr int TPW = 256 / SPT;         // threads per row
    int row = tid / TPW, sg = (tid % TPW) * SPT;
    int node = nodesS[row];
    if (node >= 0) {
      const int4* src = (const int4*)&Ls[row * 256 + sg];
      int4* dst = (int4*)&Aout[(size_t)node * 256 + sg];
      #pragma unroll
      for (int q = 0; q < SPT / 8; ++q) dst[q] = src[q];
    }
  }
}

// ---------------------------------------------------------------------------
// Setup kernel: leaf gather + weight prep + bucketing (one dispatch).
__global__ __launch_bounds__(256) void setup_k(P p) {
  __shared__ float T[64][65];
  __shared__ int cnt[8], cur[8];
  int b = blockIdx.x;
  if (b < 4096)      leaf_unit(b, p);
  else if (b < 4864) prep_tile(b - 4096, p, T);
  else               bucket_body(b - 4864, p, cnt, cur);
}

// ---------------------------------------------------------------------------
// Barrier-free fused level: each block owns 32 rows; the level is row-local
// after the gather, so G1(4ct) -> G2(2ct) -> G3 chain needs NO cross-block
// sync. a1/a2 round-trip through per-block-private global rows (same-CU RAW
// ordered by gemm_tile's entry __syncthreads vmcnt drain; L1 starts cold at
// kernel entry so no stale-line hazard from the previous level's dispatch).
// LOGIC=false: G1 fused-gather -> a1s; G2 -> a2s; G3 -> hs_out scatter.
// LOGIC=true:  LG1 fused-gather -> a1s; LG2 -> fp32 out scatter.
template<bool LOGIC>
__global__ __launch_bounds__(256, 3) void level_k(
    P p, const short* hin, short* hout, int lvl) {
  __shared__ __align__(16) short As[2 * 32 * 72];     //  9.2 KB... (2 bufs)
  __shared__ __align__(16) short Bs[2 * 128 * 72];    // 36.9 KB
  __shared__ int nodesS[32], liS[32], riS[32];

  const int bx = xcd_swizzle(blockIdx.x, gridDim.x);

  if (!LOGIC) {
    const int* ord = p.orders + lvl * PADL;
    const int* fl  = p.nf_fid + lvl * M;
    const int* gl  = p.left_idx + lvl * M;
    const int* gr  = p.right_idx + lvl * M;
    #pragma unroll
    for (int ct = 0; ct < 4; ++ct)
      gemm_tile<256, 512, 0, 1, 32>(bx, ct, nullptr, hin, gl, gr,
          p.B1T, p.b1, p.a1s, nullptr, ord, fl, As, Bs, nodesS, liS, riS);
    #pragma unroll
    for (int ct = 0; ct < 2; ++ct)
      gemm_tile<512, 256, 0, 0, 32>(bx, ct, p.a1s, nullptr, nullptr, nullptr,
          p.B2T, p.b2, p.a2s, nullptr, ord, fl, As, Bs, nodesS, liS, riS);
    gemm_tile<256, 128, 2, 0, 32>(bx, 0, p.a2s, nullptr, nullptr, nullptr,
        p.B3T, p.b3, hout, nullptr, ord, fl, As, Bs, nodesS, liS, riS);
  } else {
    const int* ordG = p.orders + L * PADL;
    #pragma unroll
    for (int ct = 0; ct < 4; ++ct)
      gemm_tile<256, 512, 0, 1, 32>(bx, ct, nullptr, hin, p.gt_left, p.gt_right,
          p.BL1T, p.bl1, p.a1s, nullptr, ordG, p.lf_fid, As, Bs, nodesS, liS, riS);
    gemm_tile<512, 128, 1, 0, 32>(bx, 0, p.a1s, nullptr, nullptr, nullptr,
        p.BL2T, p.bl2, nullptr, p.out, ordG, p.lf_fid, As, Bs, nodesS, liS, riS);
  }
}

// ---------------------------------------------------------------------------
extern "C" void kernel_launch(void* const* d_in, const int* in_sizes, int n_in,
                              void* d_out, int out_size, void* d_ws, size_t ws_size,
                              hipStream_t stream) {
  // workspace layout (~54 MB)
  const size_t SZ_H    = (size_t)M * 256 * 2;          // split-bf16 h rows
  const size_t SZ_A1   = (size_t)PADL * 1024 * 2;
  const size_t SZ_A2   = (size_t)PADL * 512 * 2;
  const size_t SZ_B1T  = (size_t)8 * 512 * 512 * 2;
  const size_t SZ_B2T  = (size_t)8 * 256 * 1024 * 2;
  const size_t SZ_B3T  = (size_t)8 * 128 * 512 * 2;
  const size_t SZ_BL1T = (size_t)4 * 512 * 512 * 2;
  const size_t SZ_BL2T = (size_t)4 * 128 * 1024 * 2;

  char* q = (char*)d_ws;
  short* hsA  = (short*)q;  q += SZ_H;
  short* hsB  = (short*)q;  q += SZ_H;
  short* a1s  = (short*)q;  q += SZ_A1;
  short* a2s  = (short*)q;  q += SZ_A2;
  short* B1T  = (short*)q;  q += SZ_B1T;
  short* B2T  = (short*)q;  q += SZ_B2T;
  short* B3T  = (short*)q;  q += SZ_B3T;
  short* BL1T = (short*)q;  q += SZ_BL1T;
  short* BL2T = (short*)q;  q += SZ_BL2T;
  int*   orders = (int*)q;

  P prm;
  prm.leaf_ids  = (const int*)d_in[0];
  prm.left_idx  = (const int*)d_in[1];
  prm.right_idx = (const int*)d_in[2];
  prm.nf_fid    = (const int*)d_in[3];
  prm.gt_left   = (const int*)d_in[4];
  prm.gt_right  = (const int*)d_in[5];
  prm.lf_fid    = (const int*)d_in[6];
  prm.emb       = (const float*)d_in[7];
  prm.W1 = (const float*)d_in[8];  prm.b1 = (const float*)d_in[9];
  prm.W2 = (const float*)d_in[10]; prm.b2 = (const float*)d_in[11];
  prm.W3 = (const float*)d_in[12]; prm.b3 = (const float*)d_in[13];
  prm.Wl1 = (const float*)d_in[14]; prm.bl1 = (const float*)d_in[15];
  prm.Wl2 = (const float*)d_in[16]; prm.bl2 = (const float*)d_in[17];
  prm.out = (float*)d_out;
  prm.hsA = hsA; prm.hsB = hsB; prm.a1s = a1s; prm.a2s = a2s;
  prm.B1T = B1T; prm.B2T = B2T; prm.B3T = B3T; prm.BL1T = BL1T; prm.BL2T = BL2T;
  prm.orders = orders;

  setup_k<<<4870, 256, 0, stream>>>(prm);       // leaf + prep + bucket

  short* hin = hsA;
  short* hout = hsB;
  for (int l = 0; l < L; ++l) {                 // 5 fused level dispatches
    level_k<false><<<PADL / 32, 256, 0, stream>>>(prm, hin, hout, l);
    short* t = hin; hin = hout; hout = t;
  }
  level_k<true><<<PADG / 32, 256, 0, stream>>>(prm, hin, nullptr, 0);
}